// Round 17
// baseline (422.331 us; speedup 1.0000x reference)
//
#include <hip/hip_runtime.h>
#include <hip/hip_fp16.h>

#define N_DIM 128
#define F_DIM 64
#define NB 256
#define TILE 2048
#define BCAP 8192

typedef _Float16 half8 __attribute__((ext_vector_type(8)));
typedef float f32x4 __attribute__((ext_vector_type(4)));

// ---------------- weight composition: Wc = W_pre @ W1 (128x64), bb = b_pre @ W1;
// also zeroes bcnt (saves a memset dispatch) ----------------
__global__ __launch_bounds__(256) void k_compose(const float* __restrict__ Wpre, const float* __restrict__ W1,
                                                 const float* __restrict__ bpre, float* __restrict__ Wc,
                                                 float* __restrict__ bb, int* __restrict__ bcnt) {
    bcnt[threadIdx.x] = 0;
    int c = threadIdx.x & 63;
    int rq = threadIdx.x >> 6;                 // 0..3
    for (int r = rq; r < N_DIM; r += 4) {
        float acc = 0.f;
        for (int k = 0; k < 64; ++k) acc = fmaf(Wpre[r * 64 + k], W1[k * 64 + c], acc);
        Wc[r * 64 + c] = acc;
    }
    if (rq == 0) {
        float acc = 0.f;
        for (int k = 0; k < 64; ++k) acc = fmaf(bpre[k], W1[k * 64 + c], acc);
        bb[c] = acc;
    }
}

// ---------------- bucket sort, phase A: single pass, LDS-staged, coalesced bucket flush ----------
__global__ __launch_bounds__(256) void k_bucket(const int* __restrict__ src, const int* __restrict__ dst,
                                                int* __restrict__ bsrc, int* __restrict__ bdst,
                                                int* __restrict__ bcnt, int e, unsigned int magic, int cap) {
    __shared__ int hist[NB], lofs[NB], gbase[NB], lcur[NB];
    __shared__ int as_[TILE], ad_[TILE];
    __shared__ unsigned char ab_[TILE];
    int tid = threadIdx.x;
    for (int t0 = blockIdx.x * TILE; t0 < e; t0 += gridDim.x * TILE) {
        int cnt = min(TILE, e - t0);
        hist[tid] = 0;
        __syncthreads();
        int dv[8], sv[8], bv[8];
#pragma unroll
        for (int j = 0; j < 8; ++j) {
            int local = j * 256 + tid;
            int idx = t0 + local;
            bool ok = local < cnt;
            dv[j] = ok ? __builtin_nontemporal_load(dst + idx) : 0;
            sv[j] = ok ? __builtin_nontemporal_load(src + idx) : 0;
            bv[j] = ok ? (int)(((unsigned long long)(unsigned)dv[j] * magic) >> 32) : -1;
            if (ok) atomicAdd(&hist[bv[j]], 1);
        }
        __syncthreads();
        int v = hist[tid];
        lofs[tid] = v;
        __syncthreads();
        for (int o = 1; o < NB; o <<= 1) {
            int x = (tid >= o) ? lofs[tid - o] : 0;
            __syncthreads();
            lofs[tid] += x;
            __syncthreads();
        }
        int excl = lofs[tid] - v;
        lofs[tid] = excl;
        lcur[tid] = excl;
        gbase[tid] = atomicAdd(&bcnt[tid], v);
        __syncthreads();
#pragma unroll
        for (int j = 0; j < 8; ++j) {
            if (bv[j] >= 0) {
                int pos = atomicAdd(&lcur[bv[j]], 1);
                as_[pos] = sv[j];
                ad_[pos] = dv[j];
                ab_[pos] = (unsigned char)bv[j];
            }
        }
        __syncthreads();
        for (int k = tid; k < cnt; k += 256) {
            int p = ab_[k];
            size_t gi = (size_t)p * cap + gbase[p] + (k - lofs[p]);
            bsrc[gi] = as_[k];
            bdst[gi] = ad_[k];
        }
        __syncthreads();
    }
}

// ---------------- phase B (fused): one block per bucket — redundant bucket-base scan,
// in-LDS counting sort, fused dinv; ALL global writes contiguous ----------
__global__ __launch_bounds__(256) void k_sort(const int* __restrict__ bsrc, const int* __restrict__ bdst,
                                              const int* __restrict__ bcnt,
                                              float* __restrict__ dinv, int* __restrict__ start,
                                              int* __restrict__ srcs, int cap, int nchunk, int n, int e) {
    __shared__ int sb[NB];
    __shared__ int lcnt[512], lcur[512];
    __shared__ int out[BCAP];
    int t = threadIdx.x;
    int b = blockIdx.x;
    int bc = bcnt[t];
    sb[t] = bc;
    __syncthreads();
    for (int o = 1; o < NB; o <<= 1) {
        int x = (t >= o) ? sb[t - o] : 0;
        __syncthreads();
        sb[t] += x;
        __syncthreads();
    }
    int base = sb[b] - bcnt[b];
    if (b == 0 && t == 0) start[n] = e;
    __syncthreads();

    int len = min(bcnt[b], min(cap, BCAP));
    int d0 = b * nchunk;
    int nloc = min(nchunk, n - d0);
    lcnt[t] = 0; lcnt[t + 256] = 0;
    __syncthreads();
    const int* bd = bdst + (size_t)b * cap;
    const int* bs = bsrc + (size_t)b * cap;
    for (int i = t; i < len; i += 256) atomicAdd(&lcnt[bd[i] - d0], 1);
    __syncthreads();
    int sv0 = lcnt[t], sv1 = lcnt[t + 256];
    for (int o = 1; o < 512; o <<= 1) {
        int x0 = (t >= o) ? lcnt[t - o] : 0;
        int x1 = (t + 256 >= o) ? lcnt[t + 256 - o] : 0;
        __syncthreads();
        lcnt[t] += x0;
        lcnt[t + 256] += x1;
        __syncthreads();
    }
    int ex0 = lcnt[t] - sv0;
    int ex1 = lcnt[t + 256] - sv1;
    lcur[t] = ex0; lcur[t + 256] = ex1;
    if (t < nloc) { start[d0 + t] = base + ex0; dinv[d0 + t] = rsqrtf((float)sv0 + 1.0f); }
    if (t + 256 < nloc) { start[d0 + t + 256] = base + ex1; dinv[d0 + t + 256] = rsqrtf((float)sv1 + 1.0f); }
    __syncthreads();
    for (int i = t; i < len; i += 256) {
        int d = bd[i] - d0;
        int pos = atomicAdd(&lcur[d], 1);
        out[pos] = bs[i];
    }
    __syncthreads();
    for (int k = t; k < len; k += 256) srcs[base + k] = out[k];
}

// ---------------- MFMA GEMM (layer 1 fused pre+linear) ----------------
// mfma_f32_16x16x32_f16 fragment layouts (m89/m91-verified family):
//   A: lane holds A[row = lane&15][k = (lane>>4)*8 + i]; C/D: col=lane&15, row=(lane>>4)*4+reg

template <int S>
__device__ inline void pack_w(const float* __restrict__ W, half8* __restrict__ Bf) {
    for (int f = threadIdx.x; f < S * 4 * 64; f += 256) {
        int l = f & 63, c = (f >> 6) & 3, s = f >> 8;
        int kbase = s * 32 + ((l >> 4) << 3);
        int col = c * 16 + (l & 15);
        half8 pk;
#pragma unroll
        for (int i = 0; i < 8; ++i) pk[i] = (_Float16)W[(kbase + i) * 64 + col];
        Bf[f] = pk;
    }
    __syncthreads();
}

// u = dinv * (x @ Wc + bb)   (N x 128)f32 @ (128 x 64), fp16 out
__global__ __launch_bounds__(256) void k_gemm_f(const float* __restrict__ X, const float* __restrict__ Wc,
                                                const float* __restrict__ bb, const float* __restrict__ dinv,
                                                __half* __restrict__ U, int n) {
    __shared__ half8 Bf[4 * 4 * 64];       // 16 KB
    pack_w<4>(Wc, Bf);
    int lane = threadIdx.x & 63;
    int row = lane & 15, kq = lane >> 4;
    float bbv0 = bb[0 * 16 + row], bbv1 = bb[1 * 16 + row], bbv2 = bb[2 * 16 + row], bbv3 = bb[3 * 16 + row];
    int gw = (blockIdx.x * 256 + threadIdx.x) >> 6;
    int nw = (gridDim.x * 256) >> 6;
    int ntile = n >> 4;
    for (int tile = gw; tile < ntile; tile += nw) {
        int r0 = tile << 4;
        const float* xp = X + (size_t)(r0 + row) * N_DIM + (kq << 3);
        f32x4 ac0 = {0.f, 0.f, 0.f, 0.f}, ac1 = ac0, ac2 = ac0, ac3 = ac0;
#pragma unroll
        for (int s = 0; s < 4; ++s) {
            float4 lo = *(const float4*)(xp + s * 32);
            float4 hi = *(const float4*)(xp + s * 32 + 4);
            half8 a;
            a[0] = (_Float16)lo.x; a[1] = (_Float16)lo.y; a[2] = (_Float16)lo.z; a[3] = (_Float16)lo.w;
            a[4] = (_Float16)hi.x; a[5] = (_Float16)hi.y; a[6] = (_Float16)hi.z; a[7] = (_Float16)hi.w;
            ac0 = __builtin_amdgcn_mfma_f32_16x16x32_f16(a, Bf[(s * 4 + 0) * 64 + lane], ac0, 0, 0, 0);
            ac1 = __builtin_amdgcn_mfma_f32_16x16x32_f16(a, Bf[(s * 4 + 1) * 64 + lane], ac1, 0, 0, 0);
            ac2 = __builtin_amdgcn_mfma_f32_16x16x32_f16(a, Bf[(s * 4 + 2) * 64 + lane], ac2, 0, 0, 0);
            ac3 = __builtin_amdgcn_mfma_f32_16x16x32_f16(a, Bf[(s * 4 + 3) * 64 + lane], ac3, 0, 0, 0);
        }
        int rbase = r0 + (kq << 2);
        float d0 = dinv[rbase + 0], d1 = dinv[rbase + 1], d2 = dinv[rbase + 2], d3 = dinv[rbase + 3];
        __half* up = U + (size_t)rbase * F_DIM + row;
        up[0 * F_DIM +  0] = __float2half(d0 * (ac0[0] + bbv0));
        up[1 * F_DIM +  0] = __float2half(d1 * (ac0[1] + bbv0));
        up[2 * F_DIM +  0] = __float2half(d2 * (ac0[2] + bbv0));
        up[3 * F_DIM +  0] = __float2half(d3 * (ac0[3] + bbv0));
        up[0 * F_DIM + 16] = __float2half(d0 * (ac1[0] + bbv1));
        up[1 * F_DIM + 16] = __float2half(d1 * (ac1[1] + bbv1));
        up[2 * F_DIM + 16] = __float2half(d2 * (ac1[2] + bbv1));
        up[3 * F_DIM + 16] = __float2half(d3 * (ac1[3] + bbv1));
        up[0 * F_DIM + 32] = __float2half(d0 * (ac2[0] + bbv2));
        up[1 * F_DIM + 32] = __float2half(d1 * (ac2[1] + bbv2));
        up[2 * F_DIM + 32] = __float2half(d2 * (ac2[2] + bbv2));
        up[3 * F_DIM + 32] = __float2half(d3 * (ac2[3] + bbv2));
        up[0 * F_DIM + 48] = __float2half(d0 * (ac3[0] + bbv3));
        up[1 * F_DIM + 48] = __float2half(d1 * (ac3[1] + bbv3));
        up[2 * F_DIM + 48] = __float2half(d2 * (ac3[2] + bbv3));
        up[3 * F_DIM + 48] = __float2half(d3 * (ac3[3] + bbv3));
    }
}

// ---------------- aggregation: ONE 8-lane group PER NODE, 8 gathers in flight,
// next-batch index prefetch. MODE 0: h=relu(...) then FUSED next-layer GEMM
// u_next = dinv*(h@Wn) via LDS-broadcast W rows + group shfl -> fp16 u out.
// MODE 1: row L2-normalize -> f32 d_out ----------------

#define PKADD(ACC, V)                                             \
    {                                                             \
        const __half2* _hp = (const __half2*)&(V);                \
        ACC[0] = __hadd2(ACC[0], _hp[0]);                         \
        ACC[1] = __hadd2(ACC[1], _hp[1]);                         \
        ACC[2] = __hadd2(ACC[2], _hp[2]);                         \
        ACC[3] = __hadd2(ACC[3], _hp[3]);                         \
    }

template <int MODE>
__global__ __launch_bounds__(256) void k_agg(const __half* __restrict__ U, const int* __restrict__ srcs,
                                             const int* __restrict__ start, const float* __restrict__ dinv,
                                             const float* __restrict__ bias, const float* __restrict__ Wn,
                                             void* __restrict__ outp, int n) {
    __shared__ __half Wl[64 * 64];         // next-layer W fp16 (MODE 0 only), 8 KB
    if (MODE == 0) {
        for (int i = threadIdx.x; i < 64 * 64; i += 256) Wl[i] = __float2half(Wn[i]);
        __syncthreads();
    }
    int lane = threadIdx.x & 63;
    int g = lane >> 3;       // node sub-group 0..7
    int t = lane & 7;        // 16B column slot within 128B row
    int node = ((blockIdx.x << 2) + (threadIdx.x >> 6)) * 8 + g;
    if (node >= n) return;   // n % 32 == 0, whole blocks only
    const float4* U4 = (const float4*)U;

    int s0 = start[node];
    int s1 = start[node + 1];

    float4 sv = U4[(size_t)node * 8 + t];
    __half2 acc[4];
    acc[0] = ((const __half2*)&sv)[0];
    acc[1] = ((const __half2*)&sv)[1];
    acc[2] = ((const __half2*)&sv)[2];
    acc[3] = ((const __half2*)&sv)[3];

    float4 z = make_float4(0.f, 0.f, 0.f, 0.f);
    int idxA[8];
#pragma unroll
    for (int j = 0; j < 8; ++j) idxA[j] = (s0 + j < s1) ? srcs[s0 + j] : 0;
    for (int p = s0; p < s1; p += 8) {
        float4 vv[8];
#pragma unroll
        for (int j = 0; j < 8; ++j)
            vv[j] = (p + j < s1) ? U4[(size_t)idxA[j] * 8 + t] : z;
        int pn = p + 8;
#pragma unroll
        for (int j = 0; j < 8; ++j)
            idxA[j] = (pn + j < s1) ? srcs[pn + j] : 0;   // prefetch next batch indices
#pragma unroll
        for (int j = 0; j < 8; ++j) PKADD(acc, vv[j]);
    }

    float2 f0 = __half22float2(acc[0]);
    float2 f1 = __half22float2(acc[1]);
    float2 f2 = __half22float2(acc[2]);
    float2 f3 = __half22float2(acc[3]);

    float di = dinv[node];
    const float4* b4 = (const float4*)bias;
    float4 bv0 = b4[2 * t], bv1 = b4[2 * t + 1];
    float v[8];
    v[0] = fmaf(di, f0.x, bv0.x); v[1] = fmaf(di, f0.y, bv0.y);
    v[2] = fmaf(di, f1.x, bv0.z); v[3] = fmaf(di, f1.y, bv0.w);
    v[4] = fmaf(di, f2.x, bv1.x); v[5] = fmaf(di, f2.y, bv1.y);
    v[6] = fmaf(di, f3.x, bv1.z); v[7] = fmaf(di, f3.y, bv1.w);

    if (MODE == 0) {
        // h = relu(v); fused next-layer GEMM: u = di * (h @ Wn)
        float hv[8];
#pragma unroll
        for (int j = 0; j < 8; ++j) hv[j] = fmaxf(v[j], 0.f);
        float ua[8] = {0.f, 0.f, 0.f, 0.f, 0.f, 0.f, 0.f, 0.f};
#pragma unroll
        for (int j = 0; j < 8; ++j) {        // j: feature offset within source lane (compile-time)
            float myv = hv[j];
#pragma unroll
            for (int ls = 0; ls < 8; ++ls) { // ls: source lane within group
                float hk = __shfl(myv, (g << 3) | ls);
                int k = ls * 8 + j;          // W row index
                float4 wq = *(const float4*)(Wl + k * 64 + t * 8);   // 8 fp16 cols, broadcast read
                const __half2* wp = (const __half2*)&wq;
                float2 w0 = __half22float2(wp[0]), w1 = __half22float2(wp[1]);
                float2 w2 = __half22float2(wp[2]), w3 = __half22float2(wp[3]);
                ua[0] = fmaf(hk, w0.x, ua[0]); ua[1] = fmaf(hk, w0.y, ua[1]);
                ua[2] = fmaf(hk, w1.x, ua[2]); ua[3] = fmaf(hk, w1.y, ua[3]);
                ua[4] = fmaf(hk, w2.x, ua[4]); ua[5] = fmaf(hk, w2.y, ua[5]);
                ua[6] = fmaf(hk, w3.x, ua[6]); ua[7] = fmaf(hk, w3.y, ua[7]);
            }
        }
        __half hr[8];
#pragma unroll
        for (int j = 0; j < 8; ++j) hr[j] = __float2half(di * ua[j]);
        *(float4*)((__half*)outp + (size_t)node * F_DIM + t * 8) = *(float4*)hr;
    } else {
        float ss = 0.f;
#pragma unroll
        for (int j = 0; j < 8; ++j) ss = fmaf(v[j], v[j], ss);
        ss += __shfl_xor(ss, 1);
        ss += __shfl_xor(ss, 2);
        ss += __shfl_xor(ss, 4);
        float inv = 1.0f / fmaxf(sqrtf(ss), 1e-12f);
        float4 r0, r1;
        r0.x = v[0] * inv; r0.y = v[1] * inv; r0.z = v[2] * inv; r0.w = v[3] * inv;
        r1.x = v[4] * inv; r1.y = v[5] * inv; r1.z = v[6] * inv; r1.w = v[7] * inv;
        float4* o4 = (float4*)((float*)outp + (size_t)node * F_DIM);
        o4[2 * t] = r0; o4[2 * t + 1] = r1;
    }
}

// ---------------- launch ----------------

extern "C" void kernel_launch(void* const* d_in, const int* in_sizes, int n_in,
                              void* d_out, int out_size, void* d_ws, size_t ws_size,
                              hipStream_t stream) {
    const float* x     = (const float*)d_in[0];
    const int*   ei    = (const int*)d_in[1];
    const float* W_pre = (const float*)d_in[2];
    const float* b_pre = (const float*)d_in[3];
    const float* W1    = (const float*)d_in[4];
    const float* b1    = (const float*)d_in[5];
    const float* Wh    = (const float*)d_in[6];
    const float* bh    = (const float*)d_in[7];
    const float* Wo    = (const float*)d_in[8];
    const float* bo    = (const float*)d_in[9];

    int n = in_sizes[0] / N_DIM;   // 100000
    int e = in_sizes[1] / 2;       // 1600000
    const int* srcIdx = ei;
    const int* dstIdx = ei + e;

    size_t off = 0;
    auto alloc = [&](size_t bytes) -> void* {
        void* p = (char*)d_ws + off;
        off += (bytes + 255) & ~(size_t)255;
        return p;
    };
    int cap = BCAP;                // per-bucket capacity (mean 6250, 24 sigma slack)

    int*    start  = (int*)alloc((size_t)(n + 1) * 4);
    float*  dinv   = (float*)alloc((size_t)n * 4);
    int*    bcnt   = (int*)alloc(NB * 4);
    int*    srcs   = (int*)alloc((size_t)e * 4);
    int*    bsrc   = (int*)alloc((size_t)NB * cap * 4);
    int*    bdst   = (int*)alloc((size_t)NB * cap * 4);
    __half* uA     = (__half*)alloc((size_t)n * F_DIM * 2);
    __half* uB     = (__half*)alloc((size_t)n * F_DIM * 2);
    float*  Wc     = (float*)alloc((size_t)N_DIM * 64 * 4);
    float*  bb     = (float*)alloc(64 * 4);

    int nbAgg = (n + 31) / 32;     // 8 nodes/wave, 4 waves/block
    int nchunk = (n + NB - 1) / NB;
    unsigned int magic = (unsigned int)(((1ull << 32) + nchunk - 1) / nchunk);

    // 0. compose layer-1 weights (also zeroes bcnt)
    k_compose<<<1, 256, 0, stream>>>(W_pre, W1, b_pre, Wc, bb, bcnt);

    // 1. bucket split (single coalesced pass over edges)
    int nbTile = (e + TILE - 1) / TILE;
    k_bucket<<<nbTile, 256, 0, stream>>>(srcIdx, dstIdx, bsrc, bdst, bcnt, e, magic, cap);

    // 2. in-LDS counting sort per bucket (bucket-base scan fused): start, dinv, srcs
    k_sort<<<NB, 256, 0, stream>>>(bsrc, bdst, bcnt, dinv, start, srcs, cap, nchunk, n, e);

    // 3. layer 1 GEMM (MFMA): u1 = dinv*(x@Wc + bb)
    k_gemm_f<<<800, 256, 0, stream>>>(x, Wc, bb, dinv, uA, n);

    // 4. agg layer 1 + fused layer-2 GEMM: u2 = dinv*(relu(dinv*Σu1 + b1) @ Wh)
    k_agg<0><<<nbAgg, 256, 0, stream>>>(uA, srcs, start, dinv, b1, Wh, uB, n);

    // 5. agg layer 2 + fused layer-3 GEMM: u3 = dinv*(relu(dinv*Σu2 + bh) @ Wo)
    k_agg<0><<<nbAgg, 256, 0, stream>>>(uB, srcs, start, dinv, bh, Wo, uA, n);

    // 6. agg layer 3 + bias + row L2 normalize -> d_out
    k_agg<1><<<nbAgg, 256, 0, stream>>>(uA, srcs, start, dinv, bo, nullptr, d_out, n);
}

// Round 18
// 281.207 us; speedup vs baseline: 1.5019x; 1.5019x over previous
//
#include <hip/hip_runtime.h>
#include <hip/hip_fp16.h>

#define N_DIM 128
#define F_DIM 64
#define NB 256
#define TILE 2048
#define BCAP 8192

typedef _Float16 half8 __attribute__((ext_vector_type(8)));
typedef float f32x4 __attribute__((ext_vector_type(4)));

// ---------------- weight composition: Wc = W_pre @ W1 (128x64), bb = b_pre @ W1;
// also zeroes bcnt (saves a memset dispatch) ----------------
__global__ __launch_bounds__(256) void k_compose(const float* __restrict__ Wpre, const float* __restrict__ W1,
                                                 const float* __restrict__ bpre, float* __restrict__ Wc,
                                                 float* __restrict__ bb, int* __restrict__ bcnt) {
    bcnt[threadIdx.x] = 0;
    int c = threadIdx.x & 63;
    int rq = threadIdx.x >> 6;                 // 0..3
    for (int r = rq; r < N_DIM; r += 4) {
        float acc = 0.f;
        for (int k = 0; k < 64; ++k) acc = fmaf(Wpre[r * 64 + k], W1[k * 64 + c], acc);
        Wc[r * 64 + c] = acc;
    }
    if (rq == 0) {
        float acc = 0.f;
        for (int k = 0; k < 64; ++k) acc = fmaf(bpre[k], W1[k * 64 + c], acc);
        bb[c] = acc;
    }
}

// ---------------- bucket sort, phase A: single pass, LDS-staged, coalesced bucket flush.
// dst stored as u16 LOCAL offset within bucket chunk (nchunk=391 < 65536) ----------------
__global__ __launch_bounds__(256) void k_bucket(const int* __restrict__ src, const int* __restrict__ dst,
                                                int* __restrict__ bsrc, unsigned short* __restrict__ bdst,
                                                int* __restrict__ bcnt, int e, unsigned int magic,
                                                int cap, int nchunk) {
    __shared__ int hist[NB], lofs[NB], gbase[NB], lcur[NB];
    __shared__ int as_[TILE];
    __shared__ unsigned short ad_[TILE];
    __shared__ unsigned char ab_[TILE];
    int tid = threadIdx.x;
    for (int t0 = blockIdx.x * TILE; t0 < e; t0 += gridDim.x * TILE) {
        int cnt = min(TILE, e - t0);
        hist[tid] = 0;
        __syncthreads();
        int dv[8], sv[8], bv[8];
#pragma unroll
        for (int j = 0; j < 8; ++j) {
            int local = j * 256 + tid;
            int idx = t0 + local;
            bool ok = local < cnt;
            dv[j] = ok ? __builtin_nontemporal_load(dst + idx) : 0;
            sv[j] = ok ? __builtin_nontemporal_load(src + idx) : 0;
            bv[j] = ok ? (int)(((unsigned long long)(unsigned)dv[j] * magic) >> 32) : -1;
            if (ok) atomicAdd(&hist[bv[j]], 1);
        }
        __syncthreads();
        int v = hist[tid];
        lofs[tid] = v;
        __syncthreads();
        for (int o = 1; o < NB; o <<= 1) {
            int x = (tid >= o) ? lofs[tid - o] : 0;
            __syncthreads();
            lofs[tid] += x;
            __syncthreads();
        }
        int excl = lofs[tid] - v;
        lofs[tid] = excl;
        lcur[tid] = excl;
        gbase[tid] = atomicAdd(&bcnt[tid], v);
        __syncthreads();
#pragma unroll
        for (int j = 0; j < 8; ++j) {
            if (bv[j] >= 0) {
                int pos = atomicAdd(&lcur[bv[j]], 1);
                as_[pos] = sv[j];
                ad_[pos] = (unsigned short)(dv[j] - bv[j] * nchunk);
                ab_[pos] = (unsigned char)bv[j];
            }
        }
        __syncthreads();
        for (int k = tid; k < cnt; k += 256) {
            int p = ab_[k];
            size_t gi = (size_t)p * cap + gbase[p] + (k - lofs[p]);
            bsrc[gi] = as_[k];
            bdst[gi] = ad_[k];
        }
        __syncthreads();
    }
}

// ---------------- phase B (fused): one block per bucket — redundant bucket-base scan,
// in-LDS counting sort, fused dinv; ALL global writes contiguous ----------
__global__ __launch_bounds__(256) void k_sort(const int* __restrict__ bsrc, const unsigned short* __restrict__ bdst,
                                              const int* __restrict__ bcnt,
                                              float* __restrict__ dinv, int* __restrict__ start,
                                              int* __restrict__ srcs, int cap, int nchunk, int n, int e) {
    __shared__ int sb[NB];
    __shared__ int lcnt[512], lcur[512];
    __shared__ int out[BCAP];
    int t = threadIdx.x;
    int b = blockIdx.x;
    int bc = bcnt[t];
    sb[t] = bc;
    __syncthreads();
    for (int o = 1; o < NB; o <<= 1) {
        int x = (t >= o) ? sb[t - o] : 0;
        __syncthreads();
        sb[t] += x;
        __syncthreads();
    }
    int base = sb[b] - bcnt[b];
    if (b == 0 && t == 0) start[n] = e;
    __syncthreads();

    int len = min(bcnt[b], min(cap, BCAP));
    int d0 = b * nchunk;
    int nloc = min(nchunk, n - d0);
    lcnt[t] = 0; lcnt[t + 256] = 0;
    __syncthreads();
    const unsigned short* bd = bdst + (size_t)b * cap;
    const int* bs = bsrc + (size_t)b * cap;
    for (int i = t; i < len; i += 256) atomicAdd(&lcnt[bd[i]], 1);
    __syncthreads();
    int sv0 = lcnt[t], sv1 = lcnt[t + 256];
    for (int o = 1; o < 512; o <<= 1) {
        int x0 = (t >= o) ? lcnt[t - o] : 0;
        int x1 = (t + 256 >= o) ? lcnt[t + 256 - o] : 0;
        __syncthreads();
        lcnt[t] += x0;
        lcnt[t + 256] += x1;
        __syncthreads();
    }
    int ex0 = lcnt[t] - sv0;
    int ex1 = lcnt[t + 256] - sv1;
    lcur[t] = ex0; lcur[t + 256] = ex1;
    if (t < nloc) { start[d0 + t] = base + ex0; dinv[d0 + t] = rsqrtf((float)sv0 + 1.0f); }
    if (t + 256 < nloc) { start[d0 + t + 256] = base + ex1; dinv[d0 + t + 256] = rsqrtf((float)sv1 + 1.0f); }
    __syncthreads();
    for (int i = t; i < len; i += 256) {
        int d = bd[i];
        int pos = atomicAdd(&lcur[d], 1);
        out[pos] = bs[i];
    }
    __syncthreads();
    for (int k = t; k < len; k += 256) srcs[base + k] = out[k];
}

// ---------------- MFMA GEMMs ----------------
// mfma_f32_16x16x32_f16 fragment layouts (m89/m91-verified family):
//   A: lane holds A[row = lane&15][k = (lane>>4)*8 + i], i=0..7 (contiguous k)
//   B: lane holds B[k = (lane>>4)*8 + i][col = lane&15]
//   C/D: col = lane&15, row = (lane>>4)*4 + reg
// B pre-packed to fragment order in LDS: frag[(s*4+c)*64 + lane] -> ds_read_b128 at lane*16.

template <int S>
__device__ inline void pack_w(const float* __restrict__ W, half8* __restrict__ Bf) {
    for (int f = threadIdx.x; f < S * 4 * 64; f += 256) {
        int l = f & 63, c = (f >> 6) & 3, s = f >> 8;
        int kbase = s * 32 + ((l >> 4) << 3);
        int col = c * 16 + (l & 15);
        half8 pk;
#pragma unroll
        for (int i = 0; i < 8; ++i) pk[i] = (_Float16)W[(kbase + i) * 64 + col];
        Bf[f] = pk;
    }
    __syncthreads();
}

// u = dinv * (x @ Wc + bb)   (N x 128)f32 @ (128 x 64), fp16 out  [layer-1 fused]
__global__ __launch_bounds__(256) void k_gemm_f(const float* __restrict__ X, const float* __restrict__ Wc,
                                                const float* __restrict__ bb, const float* __restrict__ dinv,
                                                __half* __restrict__ U, int n) {
    __shared__ half8 Bf[4 * 4 * 64];       // 16 KB
    pack_w<4>(Wc, Bf);
    int lane = threadIdx.x & 63;
    int row = lane & 15, kq = lane >> 4;
    float bbv0 = bb[0 * 16 + row], bbv1 = bb[1 * 16 + row], bbv2 = bb[2 * 16 + row], bbv3 = bb[3 * 16 + row];
    int gw = (blockIdx.x * 256 + threadIdx.x) >> 6;
    int nw = (gridDim.x * 256) >> 6;
    int ntile = n >> 4;
    for (int tile = gw; tile < ntile; tile += nw) {
        int r0 = tile << 4;
        const float* xp = X + (size_t)(r0 + row) * N_DIM + (kq << 3);
        f32x4 ac0 = {0.f, 0.f, 0.f, 0.f}, ac1 = ac0, ac2 = ac0, ac3 = ac0;
#pragma unroll
        for (int s = 0; s < 4; ++s) {
            float4 lo = *(const float4*)(xp + s * 32);
            float4 hi = *(const float4*)(xp + s * 32 + 4);
            half8 a;
            a[0] = (_Float16)lo.x; a[1] = (_Float16)lo.y; a[2] = (_Float16)lo.z; a[3] = (_Float16)lo.w;
            a[4] = (_Float16)hi.x; a[5] = (_Float16)hi.y; a[6] = (_Float16)hi.z; a[7] = (_Float16)hi.w;
            ac0 = __builtin_amdgcn_mfma_f32_16x16x32_f16(a, Bf[(s * 4 + 0) * 64 + lane], ac0, 0, 0, 0);
            ac1 = __builtin_amdgcn_mfma_f32_16x16x32_f16(a, Bf[(s * 4 + 1) * 64 + lane], ac1, 0, 0, 0);
            ac2 = __builtin_amdgcn_mfma_f32_16x16x32_f16(a, Bf[(s * 4 + 2) * 64 + lane], ac2, 0, 0, 0);
            ac3 = __builtin_amdgcn_mfma_f32_16x16x32_f16(a, Bf[(s * 4 + 3) * 64 + lane], ac3, 0, 0, 0);
        }
        int rbase = r0 + (kq << 2);
        float d0 = dinv[rbase + 0], d1 = dinv[rbase + 1], d2 = dinv[rbase + 2], d3 = dinv[rbase + 3];
        __half* up = U + (size_t)rbase * F_DIM + row;
        up[0 * F_DIM +  0] = __float2half(d0 * (ac0[0] + bbv0));
        up[1 * F_DIM +  0] = __float2half(d1 * (ac0[1] + bbv0));
        up[2 * F_DIM +  0] = __float2half(d2 * (ac0[2] + bbv0));
        up[3 * F_DIM +  0] = __float2half(d3 * (ac0[3] + bbv0));
        up[0 * F_DIM + 16] = __float2half(d0 * (ac1[0] + bbv1));
        up[1 * F_DIM + 16] = __float2half(d1 * (ac1[1] + bbv1));
        up[2 * F_DIM + 16] = __float2half(d2 * (ac1[2] + bbv1));
        up[3 * F_DIM + 16] = __float2half(d3 * (ac1[3] + bbv1));
        up[0 * F_DIM + 32] = __float2half(d0 * (ac2[0] + bbv2));
        up[1 * F_DIM + 32] = __float2half(d1 * (ac2[1] + bbv2));
        up[2 * F_DIM + 32] = __float2half(d2 * (ac2[2] + bbv2));
        up[3 * F_DIM + 32] = __float2half(d3 * (ac2[3] + bbv2));
        up[0 * F_DIM + 48] = __float2half(d0 * (ac3[0] + bbv3));
        up[1 * F_DIM + 48] = __float2half(d1 * (ac3[1] + bbv3));
        up[2 * F_DIM + 48] = __float2half(d2 * (ac3[2] + bbv3));
        up[3 * F_DIM + 48] = __float2half(d3 * (ac3[3] + bbv3));
    }
}

// u = dinv * (h @ W)   (N x 64)fp16 @ (64 x 64), fp16 out
__global__ __launch_bounds__(256) void k_gemm_l(const __half* __restrict__ H, const float* __restrict__ W,
                                                const float* __restrict__ dinv, __half* __restrict__ U, int n) {
    __shared__ half8 Bf[2 * 4 * 64];       // 8 KB
    pack_w<2>(W, Bf);
    int lane = threadIdx.x & 63;
    int row = lane & 15, kq = lane >> 4;
    int gw = (blockIdx.x * 256 + threadIdx.x) >> 6;
    int nw = (gridDim.x * 256) >> 6;
    int ntile = n >> 4;
    for (int tile = gw; tile < ntile; tile += nw) {
        int r0 = tile << 4;
        const _Float16* hp = (const _Float16*)H + (size_t)(r0 + row) * F_DIM + (kq << 3);
        half8 a0 = *(const half8*)(hp);
        half8 a1 = *(const half8*)(hp + 32);
        f32x4 ac0 = {0.f, 0.f, 0.f, 0.f}, ac1 = ac0, ac2 = ac0, ac3 = ac0;
        ac0 = __builtin_amdgcn_mfma_f32_16x16x32_f16(a0, Bf[0 * 64 + lane], ac0, 0, 0, 0);
        ac1 = __builtin_amdgcn_mfma_f32_16x16x32_f16(a0, Bf[1 * 64 + lane], ac1, 0, 0, 0);
        ac2 = __builtin_amdgcn_mfma_f32_16x16x32_f16(a0, Bf[2 * 64 + lane], ac2, 0, 0, 0);
        ac3 = __builtin_amdgcn_mfma_f32_16x16x32_f16(a0, Bf[3 * 64 + lane], ac3, 0, 0, 0);
        ac0 = __builtin_amdgcn_mfma_f32_16x16x32_f16(a1, Bf[4 * 64 + lane], ac0, 0, 0, 0);
        ac1 = __builtin_amdgcn_mfma_f32_16x16x32_f16(a1, Bf[5 * 64 + lane], ac1, 0, 0, 0);
        ac2 = __builtin_amdgcn_mfma_f32_16x16x32_f16(a1, Bf[6 * 64 + lane], ac2, 0, 0, 0);
        ac3 = __builtin_amdgcn_mfma_f32_16x16x32_f16(a1, Bf[7 * 64 + lane], ac3, 0, 0, 0);
        int rbase = r0 + (kq << 2);
        float d0 = dinv[rbase + 0], d1 = dinv[rbase + 1], d2 = dinv[rbase + 2], d3 = dinv[rbase + 3];
        __half* up = U + (size_t)rbase * F_DIM + row;
        up[0 * F_DIM +  0] = __float2half(d0 * ac0[0]);
        up[1 * F_DIM +  0] = __float2half(d1 * ac0[1]);
        up[2 * F_DIM +  0] = __float2half(d2 * ac0[2]);
        up[3 * F_DIM +  0] = __float2half(d3 * ac0[3]);
        up[0 * F_DIM + 16] = __float2half(d0 * ac1[0]);
        up[1 * F_DIM + 16] = __float2half(d1 * ac1[1]);
        up[2 * F_DIM + 16] = __float2half(d2 * ac1[2]);
        up[3 * F_DIM + 16] = __float2half(d3 * ac1[3]);
        up[0 * F_DIM + 32] = __float2half(d0 * ac2[0]);
        up[1 * F_DIM + 32] = __float2half(d1 * ac2[1]);
        up[2 * F_DIM + 32] = __float2half(d2 * ac2[2]);
        up[3 * F_DIM + 32] = __float2half(d3 * ac2[3]);
        up[0 * F_DIM + 48] = __float2half(d0 * ac3[0]);
        up[1 * F_DIM + 48] = __float2half(d1 * ac3[1]);
        up[2 * F_DIM + 48] = __float2half(d2 * ac3[2]);
        up[3 * F_DIM + 48] = __float2half(d3 * ac3[3]);
    }
}

// ---------------- aggregation: ONE 8-lane group PER NODE, 8 gathers in flight,
// next-batch index prefetch overlapped with accumulate ----------------
// MODE 0: relu -> fp16 h ; MODE 1: row L2-normalize (3-shfl group reduce) -> f32 d_out

#define PKADD(ACC, V)                                             \
    {                                                             \
        const __half2* _hp = (const __half2*)&(V);                \
        ACC[0] = __hadd2(ACC[0], _hp[0]);                         \
        ACC[1] = __hadd2(ACC[1], _hp[1]);                         \
        ACC[2] = __hadd2(ACC[2], _hp[2]);                         \
        ACC[3] = __hadd2(ACC[3], _hp[3]);                         \
    }

template <int MODE>
__global__ __launch_bounds__(256) void k_agg(const __half* __restrict__ U, const int* __restrict__ srcs,
                                             const int* __restrict__ start, const float* __restrict__ dinv,
                                             const float* __restrict__ bias, void* __restrict__ outp, int n) {
    int lane = threadIdx.x & 63;
    int g = lane >> 3;       // node sub-group 0..7
    int t = lane & 7;        // 16B column slot within 128B row
    int node = ((blockIdx.x << 2) + (threadIdx.x >> 6)) * 8 + g;
    if (node >= n) return;
    const float4* U4 = (const float4*)U;

    int s0 = start[node];
    int s1 = start[node + 1];

    // self-loop term: direct init from own row
    float4 sv = U4[(size_t)node * 8 + t];
    __half2 acc[4];
    acc[0] = ((const __half2*)&sv)[0];
    acc[1] = ((const __half2*)&sv)[1];
    acc[2] = ((const __half2*)&sv)[2];
    acc[3] = ((const __half2*)&sv)[3];

    float4 z = make_float4(0.f, 0.f, 0.f, 0.f);
    int idxA[8];
#pragma unroll
    for (int j = 0; j < 8; ++j) idxA[j] = (s0 + j < s1) ? srcs[s0 + j] : 0;
    for (int p = s0; p < s1; p += 8) {
        float4 vv[8];
#pragma unroll
        for (int j = 0; j < 8; ++j)
            vv[j] = (p + j < s1) ? U4[(size_t)idxA[j] * 8 + t] : z;
        int pn = p + 8;
#pragma unroll
        for (int j = 0; j < 8; ++j)
            idxA[j] = (pn + j < s1) ? srcs[pn + j] : 0;   // prefetch next batch indices
#pragma unroll
        for (int j = 0; j < 8; ++j) PKADD(acc, vv[j]);
    }

    float2 f0 = __half22float2(acc[0]);
    float2 f1 = __half22float2(acc[1]);
    float2 f2 = __half22float2(acc[2]);
    float2 f3 = __half22float2(acc[3]);

    float di = dinv[node];
    const float4* b4 = (const float4*)bias;
    float4 bv0 = b4[2 * t], bv1 = b4[2 * t + 1];
    float v[8];
    v[0] = fmaf(di, f0.x, bv0.x); v[1] = fmaf(di, f0.y, bv0.y);
    v[2] = fmaf(di, f1.x, bv0.z); v[3] = fmaf(di, f1.y, bv0.w);
    v[4] = fmaf(di, f2.x, bv1.x); v[5] = fmaf(di, f2.y, bv1.y);
    v[6] = fmaf(di, f3.x, bv1.z); v[7] = fmaf(di, f3.y, bv1.w);

    if (MODE == 0) {
        __half hr[8];
#pragma unroll
        for (int j = 0; j < 8; ++j) hr[j] = __float2half(fmaxf(v[j], 0.f));
        *(float4*)((__half*)outp + (size_t)node * F_DIM + t * 8) = *(float4*)hr;
    } else {
        float ss = 0.f;
#pragma unroll
        for (int j = 0; j < 8; ++j) ss = fmaf(v[j], v[j], ss);
        ss += __shfl_xor(ss, 1);
        ss += __shfl_xor(ss, 2);
        ss += __shfl_xor(ss, 4);
        float inv = 1.0f / fmaxf(sqrtf(ss), 1e-12f);
        float4 r0, r1;
        r0.x = v[0] * inv; r0.y = v[1] * inv; r0.z = v[2] * inv; r0.w = v[3] * inv;
        r1.x = v[4] * inv; r1.y = v[5] * inv; r1.z = v[6] * inv; r1.w = v[7] * inv;
        float4* o4 = (float4*)((float*)outp + (size_t)node * F_DIM);
        o4[2 * t] = r0; o4[2 * t + 1] = r1;
    }
}

// ---------------- launch ----------------

extern "C" void kernel_launch(void* const* d_in, const int* in_sizes, int n_in,
                              void* d_out, int out_size, void* d_ws, size_t ws_size,
                              hipStream_t stream) {
    const float* x     = (const float*)d_in[0];
    const int*   ei    = (const int*)d_in[1];
    const float* W_pre = (const float*)d_in[2];
    const float* b_pre = (const float*)d_in[3];
    const float* W1    = (const float*)d_in[4];
    const float* b1    = (const float*)d_in[5];
    const float* Wh    = (const float*)d_in[6];
    const float* bh    = (const float*)d_in[7];
    const float* Wo    = (const float*)d_in[8];
    const float* bo    = (const float*)d_in[9];

    int n = in_sizes[0] / N_DIM;   // 100000
    int e = in_sizes[1] / 2;       // 1600000
    const int* srcIdx = ei;
    const int* dstIdx = ei + e;

    size_t off = 0;
    auto alloc = [&](size_t bytes) -> void* {
        void* p = (char*)d_ws + off;
        off += (bytes + 255) & ~(size_t)255;
        return p;
    };
    int cap = BCAP;                // per-bucket capacity (mean 6250, 24 sigma slack)

    int*            start = (int*)alloc((size_t)(n + 1) * 4);
    float*          dinv  = (float*)alloc((size_t)n * 4);
    int*            bcnt  = (int*)alloc(NB * 4);
    int*            srcs  = (int*)alloc((size_t)e * 4);
    int*            bsrc  = (int*)alloc((size_t)NB * cap * 4);
    unsigned short* bdst  = (unsigned short*)alloc((size_t)NB * cap * 2);
    __half*         h     = (__half*)alloc((size_t)n * F_DIM * 2);
    __half*         u     = (__half*)alloc((size_t)n * F_DIM * 2);
    float*          Wc    = (float*)alloc((size_t)N_DIM * 64 * 4);
    float*          bb    = (float*)alloc(64 * 4);

    int nbAgg = (n + 31) / 32;     // 8 nodes/wave, 4 waves/block
    int nchunk = (n + NB - 1) / NB;
    unsigned int magic = (unsigned int)(((1ull << 32) + nchunk - 1) / nchunk);

    // 0. compose layer-1 weights (also zeroes bcnt)
    k_compose<<<1, 256, 0, stream>>>(W_pre, W1, b_pre, Wc, bb, bcnt);

    // 1. bucket split (single coalesced pass over edges)
    int nbTile = (e + TILE - 1) / TILE;
    k_bucket<<<nbTile, 256, 0, stream>>>(srcIdx, dstIdx, bsrc, bdst, bcnt, e, magic, cap, nchunk);

    // 2. in-LDS counting sort per bucket (bucket-base scan fused): start, dinv, srcs
    k_sort<<<NB, 256, 0, stream>>>(bsrc, bdst, bcnt, dinv, start, srcs, cap, nchunk, n, e);

    // 3. layer 1 (fused pre+linear, MFMA): u = dinv*(x@Wc + bb)
    k_gemm_f<<<800, 256, 0, stream>>>(x, Wc, bb, dinv, u, n);
    k_agg<0><<<nbAgg, 256, 0, stream>>>(u, srcs, start, dinv, b1, h, n);

    // 4. layer 2 (MFMA)
    k_gemm_l<<<800, 256, 0, stream>>>(h, Wh, dinv, u, n);
    k_agg<0><<<nbAgg, 256, 0, stream>>>(u, srcs, start, dinv, bh, h, n);

    // 5. layer 3 (MFMA) + final row L2 normalize -> d_out
    k_gemm_l<<<800, 256, 0, stream>>>(h, Wo, dinv, u, n);
    k_agg<1><<<nbAgg, 256, 0, stream>>>(u, srcs, start, dinv, bo, d_out, n);
}